// Round 6
// baseline (310.111 us; speedup 1.0000x reference)
//
#include <hip/hip_runtime.h>
#include <stdint.h>

#define NROWS 50000
#define KNB 16
#define DD 128
#define LN_EPS 1e-5f

typedef unsigned short ushort_t;
using frag_ab = __attribute__((ext_vector_type(8))) short;   // 8 bf16 (4 VGPRs)
using frag_cd = __attribute__((ext_vector_type(4))) float;   // 4 fp32 acc

static __device__ __forceinline__ float bf2f(uint32_t u) {
    union { uint32_t i; float f; } v; v.i = u << 16; return v.f;
}
static __device__ __forceinline__ ushort_t f2bf(float f) {
    union { float f; uint32_t i; } v; v.f = f;
    uint32_t x = v.i;
    return (ushort_t)((x + 0x7fffu + ((x >> 16) & 1u)) >> 16);
}
static __device__ __forceinline__ float leaky(float v) {
    return v > 0.0f ? v : 0.01f * v;
}
static __device__ __forceinline__ float tanh_fast(float z) {
    float e = __expf(2.0f * z);
    return 1.0f - 2.0f / (e + 1.0f);
}
// split fp32 -> (hi, lo) bf16 pair
static __device__ __forceinline__ void split_bf(float f, ushort_t& hi, ushort_t& lo) {
    hi = f2bf(f);
    lo = f2bf(f - bf2f(hi));
}
// packed f32x2 -> bf16x2 (RNE), single HW instr
static __device__ __forceinline__ uint32_t cvtpk(float lo, float hi) {
    uint32_t r;
    asm("v_cvt_pk_bf16_f32 %0, %1, %2" : "=v"(r) : "v"(lo), "v"(hi));
    return r;
}
// load 8 consecutive f32 of a W row -> bf16 frag (RNE, identical to f2bf)
static __device__ __forceinline__ frag_ab load_wfrag(const float* wp) {
    float4 u = *(const float4*)(wp);
    float4 v = *(const float4*)(wp + 4);
    union { uint32_t d[4]; frag_ab f; } r;
    r.d[0] = cvtpk(u.x, u.y);
    r.d[1] = cvtpk(u.z, u.w);
    r.d[2] = cvtpk(v.x, v.y);
    r.d[3] = cvtpk(v.z, v.w);
    return r.f;
}
// load 8 consecutive f32 -> hi/lo bf16 frags (full-precision A operand)
static __device__ __forceinline__ void load_afrag(const float* ip, frag_ab& hi, frag_ab& lo) {
    float4 u = *(const float4*)(ip);
    float4 v = *(const float4*)(ip + 4);
    float uu[8] = {u.x, u.y, u.z, u.w, v.x, v.y, v.z, v.w};
    #pragma unroll
    for (int i = 0; i < 8; ++i) {
        ushort_t h, l; split_bf(uu[i], h, l);
        hi[i] = (short)h; lo[i] = (short)l;
    }
}

// Streaming linear (two tasks): zero LDS, zero barriers. Wave wv owns output
// cols n0=wv*32; W-fragments live in 32 VGPRs, loaded once per block. Blocks
// [0,half) do task A (ehi,Wh,bh -> e_h); [half,2*half) task B (eti,Wt,bt -> e_t).
__global__ __launch_bounds__(256, 4) void linear_stream(
    const float* __restrict__ inA, const float* __restrict__ WA,
    const float* __restrict__ bA, float* __restrict__ outA,
    const float* __restrict__ inB, const float* __restrict__ WB,
    const float* __restrict__ bB, float* __restrict__ outB, int half)
{
    const int which = blockIdx.x >= half;
    const int bid   = which ? blockIdx.x - half : blockIdx.x;
    const float* in   = which ? inB : inA;
    const float* W    = which ? WB  : WA;
    const float* bias = which ? bB  : bA;
    float* out        = which ? outB : outA;

    const int tid  = threadIdx.x;
    const int wv   = tid >> 6;
    const int lane = tid & 63;
    const int quad = lane >> 4, lq = lane & 15;
    const int n0   = wv * 32;

    frag_ab BW[2][4];
    #pragma unroll
    for (int t = 0; t < 2; ++t) {
        const float* wr = W + (size_t)(n0 + t * 16 + lq) * DD + quad * 8;
        #pragma unroll
        for (int kc = 0; kc < 4; ++kc)
            BW[t][kc] = load_wfrag(wr + kc * 32);
    }
    float bn[2];
    #pragma unroll
    for (int t = 0; t < 2; ++t) bn[t] = bias[n0 + t * 16 + lq];

    const int ntiles = NROWS / 16;   // 3125
    for (int t0 = bid; t0 < ntiles; t0 += half) {
        const int r0 = t0 * 16;
        frag_ab Ahi[4], Alo[4];
        const float* ip = in + (size_t)(r0 + lq) * DD + quad * 8;
        #pragma unroll
        for (int kc = 0; kc < 4; ++kc)
            load_afrag(ip + kc * 32, Ahi[kc], Alo[kc]);
        #pragma unroll
        for (int t = 0; t < 2; ++t) {
            frag_cd acc = {0.f, 0.f, 0.f, 0.f};
            #pragma unroll
            for (int kc = 0; kc < 4; ++kc) {
                acc = __builtin_amdgcn_mfma_f32_16x16x32_bf16(Alo[kc], BW[t][kc], acc, 0, 0, 0);
                acc = __builtin_amdgcn_mfma_f32_16x16x32_bf16(Ahi[kc], BW[t][kc], acc, 0, 0, 0);
            }
            #pragma unroll
            for (int r = 0; r < 4; ++r)
                out[(size_t)(r0 + quad * 4 + r) * DD + n0 + t * 16 + lq] = acc[r] + bn[t];
        }
    }
}

// Mega v7 = R3 structure + 2-deep software pipeline in phase A: while row q
// computes, row q+1's idx->gather->ehv/xv chain is issued into the alternate
// register bank (q&1 is compile-time under unroll -> no scratch). idx/weight
// loads are wave-uniform -> s_loads (SGPR), only nb doubles in VGPR.
__global__ __launch_bounds__(256, 4) void mega_kernel(
    const float* e_h, const float* __restrict__ e_t,
    const int* __restrict__ topk_idx, const float* __restrict__ topk_w,
    const float* __restrict__ x,
    const float* W1, const float* __restrict__ b1,
    const float* W2, const float* __restrict__ b2,
    const float* __restrict__ gamma, const float* __restrict__ beta,
    float* out, int niters)
{
    __shared__ ushort_t aHi[16][136], aLo[16][136];   // row stride 272B (16B-aligned)
    __shared__ ushort_t mHi[16][136], mLo[16][136];
    __shared__ float hL[16][132];

    const int tid  = threadIdx.x;
    const int wv   = tid >> 6;
    const int lane = tid & 63;
    const int quad = lane >> 4, lq = lane & 15;
    const int n0   = wv * 32;   // this wave's 32 output columns

    float b1v[2], b2v[2];
    #pragma unroll
    for (int t = 0; t < 2; ++t) {
        b1v[t] = b1[n0 + t * 16 + lq];
        b2v[t] = b2[n0 + t * 16 + lq];
    }
    const float g0 = gamma[lane], g1 = gamma[lane + 64];
    const float be0 = beta[lane], be1 = beta[lane + 64];

    // per-lane W row base: row n0+lq (t=0); +16*DD for t=1
    const float* w1p = W1 + (size_t)(n0 + lq) * DD + quad * 8;
    const float* w2p = W2 + (size_t)(n0 + lq) * DD + quad * 8;

    // double-banked phase-A row state
    float2 nbb[2][KNB];
    float  pkb[2][KNB];
    float2 ehb[2], xvb[2];

    for (int c = blockIdx.x; c < niters; c += gridDim.x) {
        const int r0 = c << 4;   // 16 rows per iteration (50000 = 16*3125)

        // ---- prime row 0 of this iteration into bank 0 ----
        {
            const int nu = __builtin_amdgcn_readfirstlane(r0 + 4 * wv);
            #pragma unroll
            for (int k = 0; k < KNB; ++k) {
                int t = topk_idx[nu * KNB + k];
                t = ((unsigned)t < (unsigned)NROWS) ? t : 0;
                nbb[0][k] = *(const float2*)(e_t + (size_t)t * DD + 2 * lane);
            }
            #pragma unroll
            for (int k = 0; k < KNB; ++k) pkb[0][k] = topk_w[nu * KNB + k];
            ehb[0] = *(const float2*)(e_h + (size_t)nu * DD + 2 * lane);
            xvb[0] = *(const float2*)(x   + (size_t)nu * DD + 2 * lane);
        }

        // ---- phase A: wave wv -> rows r0+4*wv+q, pipelined 2-deep ----
        #pragma unroll
        for (int q = 0; q < 4; ++q) {
            const int cur = q & 1, nxt = cur ^ 1;
            // prefetch row q+1 into the other bank (overlaps with compute below)
            if (q < 3) {
                const int nu = __builtin_amdgcn_readfirstlane(r0 + 4 * wv + q + 1);
                #pragma unroll
                for (int k = 0; k < KNB; ++k) {
                    int t = topk_idx[nu * KNB + k];
                    t = ((unsigned)t < (unsigned)NROWS) ? t : 0;
                    nbb[nxt][k] = *(const float2*)(e_t + (size_t)t * DD + 2 * lane);
                }
                #pragma unroll
                for (int k = 0; k < KNB; ++k) pkb[nxt][k] = topk_w[nu * KNB + k];
                ehb[nxt] = *(const float2*)(e_h + (size_t)nu * DD + 2 * lane);
                xvb[nxt] = *(const float2*)(x   + (size_t)nu * DD + 2 * lane);
            }

            // compute row q from bank cur
            const int lr = 4 * wv + q;
            const float2 ehv = ehb[cur];
            const float2 xv  = xvb[cur];
            // arg = e_h + eh_r = 2*e_h + p*(nb - e_h)
            const float e2x = ehv.x + ehv.x, e2y = ehv.y + ehv.y;

            float s[KNB];
            #pragma unroll
            for (int k = 0; k < KNB; ++k) {
                const float p = pkb[cur][k];
                const float ax = __builtin_fmaf(p, nbb[cur][k].x - ehv.x, e2x);
                const float ay = __builtin_fmaf(p, nbb[cur][k].y - ehv.y, e2y);
                float part = nbb[cur][k].x * tanh_fast(ax)
                           + nbb[cur][k].y * tanh_fast(ay);
                #pragma unroll
                for (int off = 32; off >= 1; off >>= 1)
                    part += __shfl_xor(part, off, 64);
                s[k] = part;
            }
            float mx = s[0];
            #pragma unroll
            for (int k = 1; k < KNB; ++k) mx = fmaxf(mx, s[k]);
            float sum = 0.0f;
            #pragma unroll
            for (int k = 0; k < KNB; ++k) { s[k] = __expf(s[k] - mx); sum += s[k]; }
            const float inv = 1.0f / sum;
            float e0 = 0.0f, e1 = 0.0f;
            #pragma unroll
            for (int k = 0; k < KNB; ++k) { e0 += s[k] * nbb[cur][k].x; e1 += s[k] * nbb[cur][k].y; }
            e0 *= inv; e1 *= inv;

            const float a0 = xv.x + e0, a1 = xv.y + e1;
            const float m0 = xv.x * e0, m1 = xv.y * e1;
            ushort_t h0, l0, h1, l1;
            split_bf(a0, h0, l0); split_bf(a1, h1, l1);
            *(uint32_t*)(&aHi[lr][2 * lane]) = (uint32_t)h0 | ((uint32_t)h1 << 16);
            *(uint32_t*)(&aLo[lr][2 * lane]) = (uint32_t)l0 | ((uint32_t)l1 << 16);
            split_bf(m0, h0, l0); split_bf(m1, h1, l1);
            *(uint32_t*)(&mHi[lr][2 * lane]) = (uint32_t)h0 | ((uint32_t)h1 << 16);
            *(uint32_t*)(&mLo[lr][2 * lane]) = (uint32_t)l0 | ((uint32_t)l1 << 16);
        }
        __syncthreads();   // a/m staged for all 16 rows; e_h reads complete

        // ---- phase B: MFMA. A[m=lq][k] from LDS, B loaded per-kc from global ----
        {
            frag_cd aA0 = {0.f,0.f,0.f,0.f}, aA1 = {0.f,0.f,0.f,0.f};
            frag_cd aM0 = {0.f,0.f,0.f,0.f}, aM1 = {0.f,0.f,0.f,0.f};
            #pragma unroll
            for (int kc = 0; kc < 4; ++kc) {
                frag_ab B10 = load_wfrag(w1p + kc * 32);
                frag_ab B11 = load_wfrag(w1p + 16 * DD + kc * 32);
                frag_ab B20 = load_wfrag(w2p + kc * 32);
                frag_ab B21 = load_wfrag(w2p + 16 * DD + kc * 32);
                frag_ab Ah = *(const frag_ab*)(&aHi[lq][kc * 32 + quad * 8]);
                frag_ab Al = *(const frag_ab*)(&aLo[lq][kc * 32 + quad * 8]);
                frag_ab Mh = *(const frag_ab*)(&mHi[lq][kc * 32 + quad * 8]);
                frag_ab Ml = *(const frag_ab*)(&mLo[lq][kc * 32 + quad * 8]);
                aA0 = __builtin_amdgcn_mfma_f32_16x16x32_bf16(Al, B10, aA0, 0, 0, 0);
                aA0 = __builtin_amdgcn_mfma_f32_16x16x32_bf16(Ah, B10, aA0, 0, 0, 0);
                aA1 = __builtin_amdgcn_mfma_f32_16x16x32_bf16(Al, B11, aA1, 0, 0, 0);
                aA1 = __builtin_amdgcn_mfma_f32_16x16x32_bf16(Ah, B11, aA1, 0, 0, 0);
                aM0 = __builtin_amdgcn_mfma_f32_16x16x32_bf16(Ml, B20, aM0, 0, 0, 0);
                aM0 = __builtin_amdgcn_mfma_f32_16x16x32_bf16(Mh, B20, aM0, 0, 0, 0);
                aM1 = __builtin_amdgcn_mfma_f32_16x16x32_bf16(Ml, B21, aM1, 0, 0, 0);
                aM1 = __builtin_amdgcn_mfma_f32_16x16x32_bf16(Mh, B21, aM1, 0, 0, 0);
            }
            #pragma unroll
            for (int r = 0; r < 4; ++r) {
                const int row = quad * 4 + r;
                hL[row][n0 + lq]      = leaky(aA0[r] + b1v[0]) + leaky(aM0[r] + b2v[0]);
                hL[row][n0 + 16 + lq] = leaky(aA1[r] + b1v[1]) + leaky(aM1[r] + b2v[1]);
            }
        }
        __syncthreads();

        // ---- LN: wave wv -> rows 4*wv..4*wv+3; lane owns cols {lane, lane+64} ----
        #pragma unroll
        for (int q = 0; q < 4; ++q) {
            const int lr = 4 * wv + q;
            const float h0 = hL[lr][lane], h1 = hL[lr][lane + 64];
            float s = h0 + h1, qq = h0 * h0 + h1 * h1;
            #pragma unroll
            for (int off = 32; off >= 1; off >>= 1) {
                s  += __shfl_xor(s,  off, 64);
                qq += __shfl_xor(qq, off, 64);
            }
            const float mu  = s * (1.0f / DD);
            const float var = qq * (1.0f / DD) - mu * mu;
            const float rs  = rsqrtf(var + LN_EPS);
            out[(size_t)(r0 + lr) * DD + lane]      = (h0 - mu) * rs * g0 + be0;
            out[(size_t)(r0 + lr) * DD + lane + 64] = (h1 - mu) * rs * g1 + be1;
        }
        __syncthreads();   // protect LDS buffers before next iteration
    }
}

extern "C" void kernel_launch(void* const* d_in, const int* in_sizes, int n_in,
                              void* d_out, int out_size, void* d_ws, size_t ws_size,
                              hipStream_t stream) {
    const float* x      = (const float*)d_in[0];
    const float* ehi    = (const float*)d_in[1];
    const float* eti    = (const float*)d_in[2];
    const int*   tidx   = (const int*)d_in[3];
    const float* tw     = (const float*)d_in[4];
    const float* Wh     = (const float*)d_in[5];
    const float* bh     = (const float*)d_in[6];
    const float* Wt     = (const float*)d_in[7];
    const float* bt     = (const float*)d_in[8];
    const float* W1     = (const float*)d_in[9];
    const float* b1     = (const float*)d_in[10];
    const float* W2     = (const float*)d_in[11];
    const float* b2     = (const float*)d_in[12];
    const float* gamma  = (const float*)d_in[13];
    const float* beta   = (const float*)d_in[14];

    float* e_h = (float*)d_out;   // staged in fp32 output buffer (exact fit, R3-proven)
    float* e_t = (float*)d_ws;    // 25.6 MB of ws (proven)

    const int half = 1024;
    linear_stream<<<2 * half, 256, 0, stream>>>(ehi, Wh, bh, e_h,
                                                eti, Wt, bt, e_t, half);
    mega_kernel<<<1024, 256, 0, stream>>>(e_h, e_t, tidx, tw, x,
                                          W1, b1, W2, b2, gamma, beta,
                                          (float*)d_out, NROWS / 16);
}

// Round 8
// 298.633 us; speedup vs baseline: 1.0384x; 1.0384x over previous
//
#include <hip/hip_runtime.h>
#include <stdint.h>

#define NROWS 50000
#define KNB 16
#define DD 128
#define LN_EPS 1e-5f

typedef unsigned short ushort_t;
using frag_ab = __attribute__((ext_vector_type(8))) short;   // 8 bf16 (4 VGPRs)
using frag_cd = __attribute__((ext_vector_type(4))) float;   // 4 fp32 acc

static __device__ __forceinline__ float bf2f(uint32_t u) {
    union { uint32_t i; float f; } v; v.i = u << 16; return v.f;
}
static __device__ __forceinline__ ushort_t f2bf(float f) {
    union { float f; uint32_t i; } v; v.f = f;
    uint32_t x = v.i;
    return (ushort_t)((x + 0x7fffu + ((x >> 16) & 1u)) >> 16);
}
static __device__ __forceinline__ float leaky(float v) {
    return v > 0.0f ? v : 0.01f * v;
}
static __device__ __forceinline__ float tanh_fast(float z) {
    float e = __expf(2.0f * z);
    return 1.0f - 2.0f / (e + 1.0f);
}
// split fp32 -> (hi, lo) bf16 pair
static __device__ __forceinline__ void split_bf(float f, ushort_t& hi, ushort_t& lo) {
    hi = f2bf(f);
    lo = f2bf(f - bf2f(hi));
}
// packed f32x2 -> bf16x2 (RNE), single HW instr
static __device__ __forceinline__ uint32_t cvtpk(float lo, float hi) {
    uint32_t r;
    asm("v_cvt_pk_bf16_f32 %0, %1, %2" : "=v"(r) : "v"(lo), "v"(hi));
    return r;
}
// load 8 consecutive f32 of a W row -> bf16 frag (RNE, identical to f2bf)
static __device__ __forceinline__ frag_ab load_wfrag(const float* wp) {
    float4 u = *(const float4*)(wp);
    float4 v = *(const float4*)(wp + 4);
    union { uint32_t d[4]; frag_ab f; } r;
    r.d[0] = cvtpk(u.x, u.y);
    r.d[1] = cvtpk(u.z, u.w);
    r.d[2] = cvtpk(v.x, v.y);
    r.d[3] = cvtpk(v.z, v.w);
    return r.f;
}
// load 8 consecutive f32 -> hi/lo bf16 frags (full-precision A operand)
static __device__ __forceinline__ void load_afrag(const float* ip, frag_ab& hi, frag_ab& lo) {
    float4 u = *(const float4*)(ip);
    float4 v = *(const float4*)(ip + 4);
    float uu[8] = {u.x, u.y, u.z, u.w, v.x, v.y, v.z, v.w};
    #pragma unroll
    for (int i = 0; i < 8; ++i) {
        ushort_t h, l; split_bf(uu[i], h, l);
        hi[i] = (short)h; lo[i] = (short)l;
    }
}

// Streaming linear (two tasks): zero LDS, zero barriers. Wave wv owns output
// cols n0=wv*32; W-fragments live in 32 VGPRs, loaded once per block. Blocks
// [0,half) do task A (ehi,Wh,bh -> e_h); [half,2*half) task B (eti,Wt,bt -> e_t).
__global__ __launch_bounds__(256, 4) void linear_stream(
    const float* __restrict__ inA, const float* __restrict__ WA,
    const float* __restrict__ bA, float* __restrict__ outA,
    const float* __restrict__ inB, const float* __restrict__ WB,
    const float* __restrict__ bB, float* __restrict__ outB, int half)
{
    const int which = blockIdx.x >= half;
    const int bid   = which ? blockIdx.x - half : blockIdx.x;
    const float* in   = which ? inB : inA;
    const float* W    = which ? WB  : WA;
    const float* bias = which ? bB  : bA;
    float* out        = which ? outB : outA;

    const int tid  = threadIdx.x;
    const int wv   = tid >> 6;
    const int lane = tid & 63;
    const int quad = lane >> 4, lq = lane & 15;
    const int n0   = wv * 32;

    frag_ab BW[2][4];
    #pragma unroll
    for (int t = 0; t < 2; ++t) {
        const float* wr = W + (size_t)(n0 + t * 16 + lq) * DD + quad * 8;
        #pragma unroll
        for (int kc = 0; kc < 4; ++kc)
            BW[t][kc] = load_wfrag(wr + kc * 32);
    }
    float bn[2];
    #pragma unroll
    for (int t = 0; t < 2; ++t) bn[t] = bias[n0 + t * 16 + lq];

    const int ntiles = NROWS / 16;   // 3125
    for (int t0 = bid; t0 < ntiles; t0 += half) {
        const int r0 = t0 * 16;
        frag_ab Ahi[4], Alo[4];
        const float* ip = in + (size_t)(r0 + lq) * DD + quad * 8;
        #pragma unroll
        for (int kc = 0; kc < 4; ++kc)
            load_afrag(ip + kc * 32, Ahi[kc], Alo[kc]);
        #pragma unroll
        for (int t = 0; t < 2; ++t) {
            frag_cd acc = {0.f, 0.f, 0.f, 0.f};
            #pragma unroll
            for (int kc = 0; kc < 4; ++kc) {
                acc = __builtin_amdgcn_mfma_f32_16x16x32_bf16(Alo[kc], BW[t][kc], acc, 0, 0, 0);
                acc = __builtin_amdgcn_mfma_f32_16x16x32_bf16(Ahi[kc], BW[t][kc], acc, 0, 0, 0);
            }
            #pragma unroll
            for (int r = 0; r < 4; ++r)
                out[(size_t)(r0 + quad * 4 + r) * DD + n0 + t * 16 + lq] = acc[r] + bn[t];
        }
    }
}

// Mega v8 = exact R3 structure + HALF-depth phase-A pipeline: only k=0..7 of
// the next row is prefetched (+16 VGPRs, fits the 128-reg cap of
// __launch_bounds__(256,4) — R6's full 64-VGPR bank spilled to scratch).
// Row q's k=8..15 gather issues at row start (covered by k=0..7 compute);
// next row's k=0..7 gather issues mid-row (covered by k=8..15 + softmax).
// Per-k arithmetic order unchanged -> bit-identical numerics to R3.
__global__ __launch_bounds__(256, 4) void mega_kernel(
    const float* e_h, const float* __restrict__ e_t,
    const int* __restrict__ topk_idx, const float* __restrict__ topk_w,
    const float* __restrict__ x,
    const float* W1, const float* __restrict__ b1,
    const float* W2, const float* __restrict__ b2,
    const float* __restrict__ gamma, const float* __restrict__ beta,
    float* out, int niters)
{
    __shared__ ushort_t aHi[16][136], aLo[16][136];   // row stride 272B (16B-aligned)
    __shared__ ushort_t mHi[16][136], mLo[16][136];
    __shared__ float hL[16][132];

    const int tid  = threadIdx.x;
    const int wv   = tid >> 6;
    const int lane = tid & 63;
    const int quad = lane >> 4, lq = lane & 15;
    const int n0   = wv * 32;   // this wave's 32 output columns

    float b1v[2], b2v[2];
    #pragma unroll
    for (int t = 0; t < 2; ++t) {
        b1v[t] = b1[n0 + t * 16 + lq];
        b2v[t] = b2[n0 + t * 16 + lq];
    }
    const float g0 = gamma[lane], g1 = gamma[lane + 64];
    const float be0 = beta[lane], be1 = beta[lane + 64];

    // per-lane W row base: row n0+lq (t=0); +16*DD for t=1
    const float* w1p = W1 + (size_t)(n0 + lq) * DD + quad * 8;
    const float* w2p = W2 + (size_t)(n0 + lq) * DD + quad * 8;

    for (int c = blockIdx.x; c < niters; c += gridDim.x) {
        const int r0 = c << 4;   // 16 rows per iteration (50000 = 16*3125)

        // ---- prime: row 4wv+0, k=0..7 gather + ehv/xv ----
        float2 nbN[8];
        float2 ehN, xvN;
        {
            const int nu = __builtin_amdgcn_readfirstlane(r0 + 4 * wv);
            #pragma unroll
            for (int k = 0; k < 8; ++k) {
                int t = topk_idx[nu * KNB + k];
                t = ((unsigned)t < (unsigned)NROWS) ? t : 0;
                nbN[k] = *(const float2*)(e_t + (size_t)t * DD + 2 * lane);
            }
            ehN = *(const float2*)(e_h + (size_t)nu * DD + 2 * lane);
            xvN = *(const float2*)(x   + (size_t)nu * DD + 2 * lane);
        }

        // ---- phase A: wave wv -> rows r0+4*wv+q, half-pipelined ----
        #pragma unroll
        for (int q = 0; q < 4; ++q) {
            const int lr = 4 * wv + q;
            const int nu = __builtin_amdgcn_readfirstlane(r0 + lr);

            float2 nbC[KNB];
            #pragma unroll
            for (int k = 0; k < 8; ++k) nbC[k] = nbN[k];   // SSA rename after unroll
            // issue k=8..15 gather for current row (first use after k0..7 compute)
            #pragma unroll
            for (int k = 8; k < KNB; ++k) {
                int t = topk_idx[nu * KNB + k];
                t = ((unsigned)t < (unsigned)NROWS) ? t : 0;
                nbC[k] = *(const float2*)(e_t + (size_t)t * DD + 2 * lane);
            }
            float pk[KNB];
            #pragma unroll
            for (int k = 0; k < KNB; ++k) pk[k] = topk_w[nu * KNB + k];
            const float2 ehv = ehN;
            const float2 xv  = xvN;
            // arg = e_h + eh_r = 2*e_h + p*(nb - e_h)
            const float e2x = ehv.x + ehv.x, e2y = ehv.y + ehv.y;

            float s[KNB];
            // first half: k=0..7 (data ready from prefetch)
            #pragma unroll
            for (int k = 0; k < 8; ++k) {
                const float p = pk[k];
                const float ax = __builtin_fmaf(p, nbC[k].x - ehv.x, e2x);
                const float ay = __builtin_fmaf(p, nbC[k].y - ehv.y, e2y);
                float part = nbC[k].x * tanh_fast(ax)
                           + nbC[k].y * tanh_fast(ay);
                #pragma unroll
                for (int off = 32; off >= 1; off >>= 1)
                    part += __shfl_xor(part, off, 64);
                s[k] = part;
            }
            // prefetch next row's k=0..7 + ehv/xv (hidden under k8..15 + softmax)
            if (q < 3) {
                const int nu2 = __builtin_amdgcn_readfirstlane(r0 + lr + 1);
                #pragma unroll
                for (int k = 0; k < 8; ++k) {
                    int t = topk_idx[nu2 * KNB + k];
                    t = ((unsigned)t < (unsigned)NROWS) ? t : 0;
                    nbN[k] = *(const float2*)(e_t + (size_t)t * DD + 2 * lane);
                }
                ehN = *(const float2*)(e_h + (size_t)nu2 * DD + 2 * lane);
                xvN = *(const float2*)(x   + (size_t)nu2 * DD + 2 * lane);
            }
            // second half: k=8..15
            #pragma unroll
            for (int k = 8; k < KNB; ++k) {
                const float p = pk[k];
                const float ax = __builtin_fmaf(p, nbC[k].x - ehv.x, e2x);
                const float ay = __builtin_fmaf(p, nbC[k].y - ehv.y, e2y);
                float part = nbC[k].x * tanh_fast(ax)
                           + nbC[k].y * tanh_fast(ay);
                #pragma unroll
                for (int off = 32; off >= 1; off >>= 1)
                    part += __shfl_xor(part, off, 64);
                s[k] = part;
            }

            float mx = s[0];
            #pragma unroll
            for (int k = 1; k < KNB; ++k) mx = fmaxf(mx, s[k]);
            float sum = 0.0f;
            #pragma unroll
            for (int k = 0; k < KNB; ++k) { s[k] = __expf(s[k] - mx); sum += s[k]; }
            const float inv = 1.0f / sum;
            float e0 = 0.0f, e1 = 0.0f;
            #pragma unroll
            for (int k = 0; k < KNB; ++k) { e0 += s[k] * nbC[k].x; e1 += s[k] * nbC[k].y; }
            e0 *= inv; e1 *= inv;

            const float a0 = xv.x + e0, a1 = xv.y + e1;
            const float m0 = xv.x * e0, m1 = xv.y * e1;
            ushort_t h0, l0, h1, l1;
            split_bf(a0, h0, l0); split_bf(a1, h1, l1);
            *(uint32_t*)(&aHi[lr][2 * lane]) = (uint32_t)h0 | ((uint32_t)h1 << 16);
            *(uint32_t*)(&aLo[lr][2 * lane]) = (uint32_t)l0 | ((uint32_t)l1 << 16);
            split_bf(m0, h0, l0); split_bf(m1, h1, l1);
            *(uint32_t*)(&mHi[lr][2 * lane]) = (uint32_t)h0 | ((uint32_t)h1 << 16);
            *(uint32_t*)(&mLo[lr][2 * lane]) = (uint32_t)l0 | ((uint32_t)l1 << 16);
        }
        __syncthreads();   // a/m staged for all 16 rows; e_h reads complete

        // ---- phase B: MFMA. A[m=lq][k] from LDS, B loaded per-kc from global ----
        {
            frag_cd aA0 = {0.f,0.f,0.f,0.f}, aA1 = {0.f,0.f,0.f,0.f};
            frag_cd aM0 = {0.f,0.f,0.f,0.f}, aM1 = {0.f,0.f,0.f,0.f};
            #pragma unroll
            for (int kc = 0; kc < 4; ++kc) {
                frag_ab B10 = load_wfrag(w1p + kc * 32);
                frag_ab B11 = load_wfrag(w1p + 16 * DD + kc * 32);
                frag_ab B20 = load_wfrag(w2p + kc * 32);
                frag_ab B21 = load_wfrag(w2p + 16 * DD + kc * 32);
                frag_ab Ah = *(const frag_ab*)(&aHi[lq][kc * 32 + quad * 8]);
                frag_ab Al = *(const frag_ab*)(&aLo[lq][kc * 32 + quad * 8]);
                frag_ab Mh = *(const frag_ab*)(&mHi[lq][kc * 32 + quad * 8]);
                frag_ab Ml = *(const frag_ab*)(&mLo[lq][kc * 32 + quad * 8]);
                aA0 = __builtin_amdgcn_mfma_f32_16x16x32_bf16(Al, B10, aA0, 0, 0, 0);
                aA0 = __builtin_amdgcn_mfma_f32_16x16x32_bf16(Ah, B10, aA0, 0, 0, 0);
                aA1 = __builtin_amdgcn_mfma_f32_16x16x32_bf16(Al, B11, aA1, 0, 0, 0);
                aA1 = __builtin_amdgcn_mfma_f32_16x16x32_bf16(Ah, B11, aA1, 0, 0, 0);
                aM0 = __builtin_amdgcn_mfma_f32_16x16x32_bf16(Ml, B20, aM0, 0, 0, 0);
                aM0 = __builtin_amdgcn_mfma_f32_16x16x32_bf16(Mh, B20, aM0, 0, 0, 0);
                aM1 = __builtin_amdgcn_mfma_f32_16x16x32_bf16(Ml, B21, aM1, 0, 0, 0);
                aM1 = __builtin_amdgcn_mfma_f32_16x16x32_bf16(Mh, B21, aM1, 0, 0, 0);
            }
            #pragma unroll
            for (int r = 0; r < 4; ++r) {
                const int row = quad * 4 + r;
                hL[row][n0 + lq]      = leaky(aA0[r] + b1v[0]) + leaky(aM0[r] + b2v[0]);
                hL[row][n0 + 16 + lq] = leaky(aA1[r] + b1v[1]) + leaky(aM1[r] + b2v[1]);
            }
        }
        __syncthreads();

        // ---- LN: wave wv -> rows 4*wv..4*wv+3; lane owns cols {lane, lane+64} ----
        #pragma unroll
        for (int q = 0; q < 4; ++q) {
            const int lr = 4 * wv + q;
            const float h0 = hL[lr][lane], h1 = hL[lr][lane + 64];
            float s = h0 + h1, qq = h0 * h0 + h1 * h1;
            #pragma unroll
            for (int off = 32; off >= 1; off >>= 1) {
                s  += __shfl_xor(s,  off, 64);
                qq += __shfl_xor(qq, off, 64);
            }
            const float mu  = s * (1.0f / DD);
            const float var = qq * (1.0f / DD) - mu * mu;
            const float rs  = rsqrtf(var + LN_EPS);
            out[(size_t)(r0 + lr) * DD + lane]      = (h0 - mu) * rs * g0 + be0;
            out[(size_t)(r0 + lr) * DD + lane + 64] = (h1 - mu) * rs * g1 + be1;
        }
        __syncthreads();   // protect LDS buffers before next iteration
    }
}

extern "C" void kernel_launch(void* const* d_in, const int* in_sizes, int n_in,
                              void* d_out, int out_size, void* d_ws, size_t ws_size,
                              hipStream_t stream) {
    const float* x      = (const float*)d_in[0];
    const float* ehi    = (const float*)d_in[1];
    const float* eti    = (const float*)d_in[2];
    const int*   tidx   = (const int*)d_in[3];
    const float* tw     = (const float*)d_in[4];
    const float* Wh     = (const float*)d_in[5];
    const float* bh     = (const float*)d_in[6];
    const float* Wt     = (const float*)d_in[7];
    const float* bt     = (const float*)d_in[8];
    const float* W1     = (const float*)d_in[9];
    const float* b1     = (const float*)d_in[10];
    const float* W2     = (const float*)d_in[11];
    const float* b2     = (const float*)d_in[12];
    const float* gamma  = (const float*)d_in[13];
    const float* beta   = (const float*)d_in[14];

    float* e_h = (float*)d_out;   // staged in fp32 output buffer (exact fit, R3-proven)
    float* e_t = (float*)d_ws;    // 25.6 MB of ws (proven)

    const int half = 1024;
    linear_stream<<<2 * half, 256, 0, stream>>>(ehi, Wh, bh, e_h,
                                                eti, Wt, bt, e_t, half);
    mega_kernel<<<1024, 256, 0, stream>>>(e_h, e_t, tidx, tw, x,
                                          W1, b1, W2, b2, gamma, beta,
                                          (float*)d_out, NROWS / 16);
}

// Round 9
// 297.100 us; speedup vs baseline: 1.0438x; 1.0052x over previous
//
#include <hip/hip_runtime.h>
#include <stdint.h>

#define NROWS 50000
#define KNB 16
#define DD 128
#define LN_EPS 1e-5f

typedef unsigned short ushort_t;
using frag_ab = __attribute__((ext_vector_type(8))) short;   // 8 bf16 (4 VGPRs)
using frag_cd = __attribute__((ext_vector_type(4))) float;   // 4 fp32 acc

static __device__ __forceinline__ float bf2f(uint32_t u) {
    union { uint32_t i; float f; } v; v.i = u << 16; return v.f;
}
static __device__ __forceinline__ ushort_t f2bf(float f) {
    union { float f; uint32_t i; } v; v.f = f;
    uint32_t x = v.i;
    return (ushort_t)((x + 0x7fffu + ((x >> 16) & 1u)) >> 16);
}
static __device__ __forceinline__ float leaky(float v) {
    return v > 0.0f ? v : 0.01f * v;
}
static __device__ __forceinline__ float tanh_fast(float z) {
    float e = __expf(2.0f * z);
    return 1.0f - 2.0f / (e + 1.0f);
}
// split fp32 -> (hi, lo) bf16 pair
static __device__ __forceinline__ void split_bf(float f, ushort_t& hi, ushort_t& lo) {
    hi = f2bf(f);
    lo = f2bf(f - bf2f(hi));
}
// packed f32x2 -> bf16x2 (RNE), single HW instr
static __device__ __forceinline__ uint32_t cvtpk(float lo, float hi) {
    uint32_t r;
    asm("v_cvt_pk_bf16_f32 %0, %1, %2" : "=v"(r) : "v"(lo), "v"(hi));
    return r;
}
// load 8 consecutive f32 of a W row -> bf16 frag (RNE, identical to f2bf)
static __device__ __forceinline__ frag_ab load_wfrag(const float* wp) {
    float4 u = *(const float4*)(wp);
    float4 v = *(const float4*)(wp + 4);
    union { uint32_t d[4]; frag_ab f; } r;
    r.d[0] = cvtpk(u.x, u.y);
    r.d[1] = cvtpk(u.z, u.w);
    r.d[2] = cvtpk(v.x, v.y);
    r.d[3] = cvtpk(v.z, v.w);
    return r.f;
}
// load 8 consecutive f32 -> hi/lo bf16 frags (full-precision A operand)
static __device__ __forceinline__ void load_afrag(const float* ip, frag_ab& hi, frag_ab& lo) {
    float4 u = *(const float4*)(ip);
    float4 v = *(const float4*)(ip + 4);
    float uu[8] = {u.x, u.y, u.z, u.w, v.x, v.y, v.z, v.w};
    #pragma unroll
    for (int i = 0; i < 8; ++i) {
        ushort_t h, l; split_bf(uu[i], h, l);
        hi[i] = (short)h; lo[i] = (short)l;
    }
}

// Streaming linear (two tasks): zero LDS, zero barriers. Wave wv owns output
// cols n0=wv*32; W-fragments live in 32 VGPRs, loaded once per block. Blocks
// [0,half) do task A (ehi,Wh,bh -> e_h); [half,2*half) task B (eti,Wt,bt -> e_t).
__global__ __launch_bounds__(256, 4) void linear_stream(
    const float* __restrict__ inA, const float* __restrict__ WA,
    const float* __restrict__ bA, float* __restrict__ outA,
    const float* __restrict__ inB, const float* __restrict__ WB,
    const float* __restrict__ bB, float* __restrict__ outB, int half)
{
    const int which = blockIdx.x >= half;
    const int bid   = which ? blockIdx.x - half : blockIdx.x;
    const float* in   = which ? inB : inA;
    const float* W    = which ? WB  : WA;
    const float* bias = which ? bB  : bA;
    float* out        = which ? outB : outA;

    const int tid  = threadIdx.x;
    const int wv   = tid >> 6;
    const int lane = tid & 63;
    const int quad = lane >> 4, lq = lane & 15;
    const int n0   = wv * 32;

    frag_ab BW[2][4];
    #pragma unroll
    for (int t = 0; t < 2; ++t) {
        const float* wr = W + (size_t)(n0 + t * 16 + lq) * DD + quad * 8;
        #pragma unroll
        for (int kc = 0; kc < 4; ++kc)
            BW[t][kc] = load_wfrag(wr + kc * 32);
    }
    float bn[2];
    #pragma unroll
    for (int t = 0; t < 2; ++t) bn[t] = bias[n0 + t * 16 + lq];

    const int ntiles = NROWS / 16;   // 3125
    for (int t0 = bid; t0 < ntiles; t0 += half) {
        const int r0 = t0 * 16;
        frag_ab Ahi[4], Alo[4];
        const float* ip = in + (size_t)(r0 + lq) * DD + quad * 8;
        #pragma unroll
        for (int kc = 0; kc < 4; ++kc)
            load_afrag(ip + kc * 32, Ahi[kc], Alo[kc]);
        #pragma unroll
        for (int t = 0; t < 2; ++t) {
            frag_cd acc = {0.f, 0.f, 0.f, 0.f};
            #pragma unroll
            for (int kc = 0; kc < 4; ++kc) {
                acc = __builtin_amdgcn_mfma_f32_16x16x32_bf16(Alo[kc], BW[t][kc], acc, 0, 0, 0);
                acc = __builtin_amdgcn_mfma_f32_16x16x32_bf16(Ahi[kc], BW[t][kc], acc, 0, 0, 0);
            }
            #pragma unroll
            for (int r = 0; r < 4; ++r)
                out[(size_t)(r0 + quad * 4 + r) * DD + n0 + t * 16 + lq] = acc[r] + bn[t];
        }
    }
}

// Mega v9 = exact R3 phase A (no pipeline — both pipelining attempts spilled)
// + hL/LN EVICTED from the kernel: phase B stores h directly to out, LN runs
// as a separate kernel. LDS 26112 -> 17408 B. This tests the hypothesis that
// the ~3-blocks/CU residency cap is the usable-LDS pool (~96KB/26K=3).
__global__ __launch_bounds__(256, 4) void mega_kernel(
    const float* e_h, const float* __restrict__ e_t,
    const int* __restrict__ topk_idx, const float* __restrict__ topk_w,
    const float* __restrict__ x,
    const float* W1, const float* __restrict__ b1,
    const float* W2, const float* __restrict__ b2,
    float* out, int niters)
{
    __shared__ ushort_t aHi[16][136], aLo[16][136];   // row stride 272B (16B-aligned)
    __shared__ ushort_t mHi[16][136], mLo[16][136];

    const int tid  = threadIdx.x;
    const int wv   = tid >> 6;
    const int lane = tid & 63;
    const int quad = lane >> 4, lq = lane & 15;
    const int n0   = wv * 32;   // this wave's 32 output columns

    float b1v[2], b2v[2];
    #pragma unroll
    for (int t = 0; t < 2; ++t) {
        b1v[t] = b1[n0 + t * 16 + lq];
        b2v[t] = b2[n0 + t * 16 + lq];
    }

    // per-lane W row base: row n0+lq (t=0); +16*DD for t=1
    const float* w1p = W1 + (size_t)(n0 + lq) * DD + quad * 8;
    const float* w2p = W2 + (size_t)(n0 + lq) * DD + quad * 8;

    for (int c = blockIdx.x; c < niters; c += gridDim.x) {
        const int r0 = c << 4;   // 16 rows per iteration (50000 = 16*3125)

        // ---- phase A: wave wv -> rows r0+4*wv+q; lane owns dims {2*lane, 2*lane+1} ----
        #pragma unroll
        for (int q = 0; q < 4; ++q) {
            const int lr = 4 * wv + q;
            const int nu = __builtin_amdgcn_readfirstlane(r0 + lr);
            int   tk[KNB];
            float pk[KNB];
            #pragma unroll
            for (int k = 0; k < KNB; ++k) tk[k] = topk_idx[nu * KNB + k];
            #pragma unroll
            for (int k = 0; k < KNB; ++k) pk[k] = topk_w[nu * KNB + k];
            float2 nb[KNB];
            #pragma unroll
            for (int k = 0; k < KNB; ++k) {
                int t = tk[k];
                t = ((unsigned)t < (unsigned)NROWS) ? t : 0;
                nb[k] = *(const float2*)(e_t + (size_t)t * DD + 2 * lane);
            }
            const float2 ehv = *(const float2*)(e_h + (size_t)nu * DD + 2 * lane);
            const float2 xv  = *(const float2*)(x   + (size_t)nu * DD + 2 * lane);

            // arg = e_h + eh_r = 2*e_h + p*(nb - e_h)
            const float e2x = ehv.x + ehv.x, e2y = ehv.y + ehv.y;

            float s[KNB];
            #pragma unroll
            for (int k = 0; k < KNB; ++k) {
                const float p = pk[k];
                const float ax = __builtin_fmaf(p, nb[k].x - ehv.x, e2x);
                const float ay = __builtin_fmaf(p, nb[k].y - ehv.y, e2y);
                float part = nb[k].x * tanh_fast(ax)
                           + nb[k].y * tanh_fast(ay);
                #pragma unroll
                for (int off = 32; off >= 1; off >>= 1)
                    part += __shfl_xor(part, off, 64);
                s[k] = part;
            }
            float mx = s[0];
            #pragma unroll
            for (int k = 1; k < KNB; ++k) mx = fmaxf(mx, s[k]);
            float sum = 0.0f;
            #pragma unroll
            for (int k = 0; k < KNB; ++k) { s[k] = __expf(s[k] - mx); sum += s[k]; }
            const float inv = 1.0f / sum;
            float e0 = 0.0f, e1 = 0.0f;
            #pragma unroll
            for (int k = 0; k < KNB; ++k) { e0 += s[k] * nb[k].x; e1 += s[k] * nb[k].y; }
            e0 *= inv; e1 *= inv;

            const float a0 = xv.x + e0, a1 = xv.y + e1;
            const float m0 = xv.x * e0, m1 = xv.y * e1;
            ushort_t h0, l0, h1, l1;
            split_bf(a0, h0, l0); split_bf(a1, h1, l1);
            *(uint32_t*)(&aHi[lr][2 * lane]) = (uint32_t)h0 | ((uint32_t)h1 << 16);
            *(uint32_t*)(&aLo[lr][2 * lane]) = (uint32_t)l0 | ((uint32_t)l1 << 16);
            split_bf(m0, h0, l0); split_bf(m1, h1, l1);
            *(uint32_t*)(&mHi[lr][2 * lane]) = (uint32_t)h0 | ((uint32_t)h1 << 16);
            *(uint32_t*)(&mLo[lr][2 * lane]) = (uint32_t)l0 | ((uint32_t)l1 << 16);
        }
        __syncthreads();   // a/m staged for all 16 rows; e_h reads complete

        // ---- phase B: MFMA. A[m=lq][k] from LDS, B loaded per-kc from global.
        //      h stored DIRECTLY to out (LN runs as a separate kernel). ----
        {
            frag_cd aA0 = {0.f,0.f,0.f,0.f}, aA1 = {0.f,0.f,0.f,0.f};
            frag_cd aM0 = {0.f,0.f,0.f,0.f}, aM1 = {0.f,0.f,0.f,0.f};
            #pragma unroll
            for (int kc = 0; kc < 4; ++kc) {
                frag_ab B10 = load_wfrag(w1p + kc * 32);
                frag_ab B11 = load_wfrag(w1p + 16 * DD + kc * 32);
                frag_ab B20 = load_wfrag(w2p + kc * 32);
                frag_ab B21 = load_wfrag(w2p + 16 * DD + kc * 32);
                frag_ab Ah = *(const frag_ab*)(&aHi[lq][kc * 32 + quad * 8]);
                frag_ab Al = *(const frag_ab*)(&aLo[lq][kc * 32 + quad * 8]);
                frag_ab Mh = *(const frag_ab*)(&mHi[lq][kc * 32 + quad * 8]);
                frag_ab Ml = *(const frag_ab*)(&mLo[lq][kc * 32 + quad * 8]);
                aA0 = __builtin_amdgcn_mfma_f32_16x16x32_bf16(Al, B10, aA0, 0, 0, 0);
                aA0 = __builtin_amdgcn_mfma_f32_16x16x32_bf16(Ah, B10, aA0, 0, 0, 0);
                aA1 = __builtin_amdgcn_mfma_f32_16x16x32_bf16(Al, B11, aA1, 0, 0, 0);
                aA1 = __builtin_amdgcn_mfma_f32_16x16x32_bf16(Ah, B11, aA1, 0, 0, 0);
                aM0 = __builtin_amdgcn_mfma_f32_16x16x32_bf16(Ml, B20, aM0, 0, 0, 0);
                aM0 = __builtin_amdgcn_mfma_f32_16x16x32_bf16(Mh, B20, aM0, 0, 0, 0);
                aM1 = __builtin_amdgcn_mfma_f32_16x16x32_bf16(Ml, B21, aM1, 0, 0, 0);
                aM1 = __builtin_amdgcn_mfma_f32_16x16x32_bf16(Mh, B21, aM1, 0, 0, 0);
            }
            #pragma unroll
            for (int r = 0; r < 4; ++r) {
                const size_t gr = (size_t)(r0 + quad * 4 + r) * DD;
                out[gr + n0 + lq]      = leaky(aA0[r] + b1v[0]) + leaky(aM0[r] + b2v[0]);
                out[gr + n0 + 16 + lq] = leaky(aA1[r] + b1v[1]) + leaky(aM1[r] + b2v[1]);
            }
        }
        __syncthreads();   // protect LDS buffers before next iteration
    }
}

// In-place LayerNorm over out rows: wave per row, lane owns cols {lane, lane+64}.
__global__ __launch_bounds__(256) void ln_kernel(
    float* out, const float* __restrict__ gamma, const float* __restrict__ beta)
{
    const int wv   = threadIdx.x >> 6;
    const int lane = threadIdx.x & 63;
    const float g0 = gamma[lane], g1 = gamma[lane + 64];
    const float be0 = beta[lane], be1 = beta[lane + 64];

    for (int r = blockIdx.x * 4 + wv; r < NROWS; r += gridDim.x * 4) {
        float* rp = out + (size_t)r * DD;
        const float h0 = rp[lane], h1 = rp[lane + 64];
        float s = h0 + h1, qq = h0 * h0 + h1 * h1;
        #pragma unroll
        for (int off = 32; off >= 1; off >>= 1) {
            s  += __shfl_xor(s,  off, 64);
            qq += __shfl_xor(qq, off, 64);
        }
        const float mu  = s * (1.0f / DD);
        const float var = qq * (1.0f / DD) - mu * mu;
        const float rs  = rsqrtf(var + LN_EPS);
        rp[lane]      = (h0 - mu) * rs * g0 + be0;
        rp[lane + 64] = (h1 - mu) * rs * g1 + be1;
    }
}

extern "C" void kernel_launch(void* const* d_in, const int* in_sizes, int n_in,
                              void* d_out, int out_size, void* d_ws, size_t ws_size,
                              hipStream_t stream) {
    const float* x      = (const float*)d_in[0];
    const float* ehi    = (const float*)d_in[1];
    const float* eti    = (const float*)d_in[2];
    const int*   tidx   = (const int*)d_in[3];
    const float* tw     = (const float*)d_in[4];
    const float* Wh     = (const float*)d_in[5];
    const float* bh     = (const float*)d_in[6];
    const float* Wt     = (const float*)d_in[7];
    const float* bt     = (const float*)d_in[8];
    const float* W1     = (const float*)d_in[9];
    const float* b1     = (const float*)d_in[10];
    const float* W2     = (const float*)d_in[11];
    const float* b2     = (const float*)d_in[12];
    const float* gamma  = (const float*)d_in[13];
    const float* beta   = (const float*)d_in[14];

    float* e_h = (float*)d_out;   // staged in fp32 output buffer (exact fit, R3-proven)
    float* e_t = (float*)d_ws;    // 25.6 MB of ws (proven)

    const int half = 1024;
    linear_stream<<<2 * half, 256, 0, stream>>>(ehi, Wh, bh, e_h,
                                                eti, Wt, bt, e_t, half);
    mega_kernel<<<1024, 256, 0, stream>>>(e_h, e_t, tidx, tw, x,
                                          W1, b1, W2, b2,
                                          (float*)d_out, NROWS / 16);
    ln_kernel<<<2048, 256, 0, stream>>>((float*)d_out, gamma, beta);
}